// Round 1
// baseline (775.334 us; speedup 1.0000x reference)
//
#include <hip/hip_runtime.h>
#include <cstdint>
#include <cstddef>

typedef __bf16 bf16x8 __attribute__((ext_vector_type(8)));
typedef float  f32x16 __attribute__((ext_vector_type(16)));

__device__ __forceinline__ unsigned f2bf_u(float f){
  unsigned u = __float_as_uint(f);
  return (u + 0x7FFFu + ((u >> 16) & 1u)) >> 16;   // RNE
}
__device__ __forceinline__ unsigned pk2(float a, float b){
  return f2bf_u(a) | (f2bf_u(b) << 16);
}
__device__ __forceinline__ unsigned short f2bf(float f){
  return (unsigned short)f2bf_u(f);
}
__device__ __forceinline__ float fast_tanh(float x){
  float xx = fminf(fmaxf(x, -8.0f), 8.0f);
  float e  = __builtin_amdgcn_exp2f(xx * 2.8853900817779268f);  // exp(2x)
  return 1.0f - 2.0f * __builtin_amdgcn_rcpf(e + 1.0f);
}

#define MFMA(a,b,c) __builtin_amdgcn_mfma_f32_32x32x16_bf16((a),(b),(c),0,0,0)

// Block: 32 n-rows (=128 x-rows), 256 threads = 4 waves.
// Wave w owns x-rows [32w,32w+32): A frags live in registers (64 VGPR).
// Stage1: 8 g-chunks of 32 cols; GEMM cols = k*32+g (k = acc tile index).
// Combine (tanh + 12 perms) fully in-register, nei/3 -> LDS bf16.
// Stage2/3: 32x256x256 GEMMs from LDS with W1/W2 streamed through LDS.
__launch_bounds__(256, 2)
__global__ void tetra_fused(const float* __restrict__ x,
                            const float* __restrict__ Wb,
                            const float* __restrict__ bb,
                            const float* __restrict__ W1,
                            const float* __restrict__ b1,
                            const float* __restrict__ gam,
                            const float* __restrict__ bet,
                            const float* __restrict__ W2,
                            const float* __restrict__ b2,
                            float* __restrict__ out)
{
  constexpr int H    = 256;
  constexpr int BSTR = 40;    // LDS B stride (bf16 units): 80B rows, 16B aligned, padded
  constexpr int NSTR = 264;   // nei3 stride: 528B rows, 16B aligned, padded

  __shared__ __align__(16) unsigned short Bl[256*BSTR];    // 20480 B
  __shared__ __align__(16) unsigned short nei3[32*NSTR];   // 16896 B

  // A4 rotation group: even perms of {0,1,2,3} (matches reference table)
  constexpr int PT[12][4] = {{0,1,2,3},{0,2,3,1},{0,3,1,2},{1,0,3,2},{1,2,0,3},{1,3,2,0},
                             {2,0,1,3},{2,1,3,0},{2,3,0,1},{3,0,2,1},{3,1,0,2},{3,2,1,0}};

  const int tid  = threadIdx.x;
  const int w    = tid >> 6;
  const int lane = tid & 63;
  const int l31  = lane & 31;
  const int q    = lane >> 5;

  // ---- A tile -> registers. Lane covers row (lane&31) of wave slab, k-granule q.
  uint4 fragA[16];
  {
    const float* arow = x + ((size_t)blockIdx.x*128 + (size_t)(w*32 + l31))*H + q*8;
#pragma unroll
    for (int s = 0; s < 16; ++s){
      float4 f0 = *reinterpret_cast<const float4*>(arow + s*16);
      float4 f1 = *reinterpret_cast<const float4*>(arow + s*16 + 4);
      fragA[s] = make_uint4(pk2(f0.x,f0.y), pk2(f0.z,f0.w), pk2(f1.x,f1.y), pk2(f1.z,f1.w));
    }
  }

  const int scol = tid >> 1;          // staging col 0..127 (2 threads/col)
  const int sc4  = (tid & 1) * 4;     // which 4 float4-granules

  // ================= stage 1 =================
  for (int gc = 0; gc < 8; ++gc){
    const int g0 = gc * 32;
    const float* bp = Wb + ((size_t)((scol >> 5)*256 + g0 + (scol & 31)))*H;

    f32x16 acc[4];
#pragma unroll
    for (int t = 0; t < 4; ++t)
#pragma unroll
      for (int r = 0; r < 16; ++r) acc[t][r] = 0.0f;

    float4 bst[4];
#pragma unroll
    for (int i = 0; i < 4; ++i)
      bst[i] = *reinterpret_cast<const float4*>(bp + (sc4 + i)*4);

    for (int kb = 0; kb < 8; ++kb){
      __syncthreads();
#pragma unroll
      for (int i = 0; i < 4; ++i){
        float4 f = bst[i];
        *reinterpret_cast<uint2*>(&Bl[scol*BSTR + (sc4 + i)*4]) =
            make_uint2(pk2(f.x,f.y), pk2(f.z,f.w));
      }
      __syncthreads();
      if (kb < 7){
#pragma unroll
        for (int i = 0; i < 4; ++i)
          bst[i] = *reinterpret_cast<const float4*>(bp + (kb+1)*32 + (sc4 + i)*4);
      }
#pragma unroll
      for (int ss = 0; ss < 2; ++ss){
        bf16x8 av = __builtin_bit_cast(bf16x8, fragA[kb*2 + ss]);
#pragma unroll
        for (int tj = 0; tj < 4; ++tj){
          bf16x8 bv = *reinterpret_cast<const bf16x8*>(&Bl[(tj*32 + l31)*BSTR + ss*16 + q*8]);
          acc[tj] = MFMA(av, bv, acc[tj]);
        }
      }
    }

    // epilogue: bias + tanh in place; in-register 12-perm combine
    float bbv[4];
#pragma unroll
    for (int k = 0; k < 4; ++k) bbv[k] = bb[k*H + g0 + l31];
#pragma unroll
    for (int k = 0; k < 4; ++k)
#pragma unroll
      for (int r = 0; r < 16; ++r)
        acc[k][r] = fast_tanh(acc[k][r] + bbv[k]);

#pragma unroll
    for (int nb = 0; nb < 4; ++nb){
      float s = 0.0f;
#pragma unroll
      for (int p = 0; p < 12; ++p){
        float v = acc[0][nb*4 + PT[p][0]] + acc[1][nb*4 + PT[p][1]]
                + acc[2][nb*4 + PT[p][2]] + acc[3][nb*4 + PT[p][3]];
        s += fmaxf(v, 0.0f);
      }
      nei3[(w*8 + 2*nb + q)*NSTR + g0 + l31] = f2bf(s * (1.0f/3.0f));
    }
  }

  // ================= stage 2: z = (nei/3)@W1^T + b1 ; h = relu(z*inv*gamma+beta) =================
  {
    f32x16 acc2[2];
#pragma unroll
    for (int t = 0; t < 2; ++t)
#pragma unroll
      for (int r = 0; r < 16; ++r) acc2[t][r] = 0.0f;

    const float* wp = W1 + (size_t)tid*H;
    for (int kb = 0; kb < 8; ++kb){
      __syncthreads();
#pragma unroll
      for (int i = 0; i < 8; ++i){
        float4 f = *reinterpret_cast<const float4*>(wp + kb*32 + i*4);
        *reinterpret_cast<uint2*>(&Bl[tid*BSTR + i*4]) = make_uint2(pk2(f.x,f.y), pk2(f.z,f.w));
      }
      __syncthreads();
#pragma unroll
      for (int ss = 0; ss < 2; ++ss){
        bf16x8 av = *reinterpret_cast<const bf16x8*>(&nei3[l31*NSTR + kb*32 + ss*16 + q*8]);
#pragma unroll
        for (int tj = 0; tj < 2; ++tj){
          bf16x8 bv = *reinterpret_cast<const bf16x8*>(&Bl[(w*64 + tj*32 + l31)*BSTR + ss*16 + q*8]);
          acc2[tj] = MFMA(av, bv, acc2[tj]);
        }
      }
    }
    __syncthreads();                         // all nei3 reads done before overwrite
    const float inv = 0.9999950000374998f;   // 1/sqrt(1+1e-5)
#pragma unroll
    for (int tj = 0; tj < 2; ++tj){
      int col = w*64 + tj*32 + l31;
      float b1v = b1[col], gv = gam[col], btv = bet[col];
#pragma unroll
      for (int r = 0; r < 16; ++r){
        int row = (r&3) + 8*(r>>2) + 4*q;
        float z  = acc2[tj][r] + b1v;
        float hv = fmaxf(z*inv*gv + btv, 0.0f);
        nei3[row*NSTR + col] = f2bf(hv);     // h overwrites nei buffer
      }
    }
    __syncthreads();
  }

  // ================= stage 3: out = h@W2^T + b2 =================
  {
    f32x16 acc2[2];
#pragma unroll
    for (int t = 0; t < 2; ++t)
#pragma unroll
      for (int r = 0; r < 16; ++r) acc2[t][r] = 0.0f;

    const float* wp = W2 + (size_t)tid*H;
    for (int kb = 0; kb < 8; ++kb){
      __syncthreads();
#pragma unroll
      for (int i = 0; i < 8; ++i){
        float4 f = *reinterpret_cast<const float4*>(wp + kb*32 + i*4);
        *reinterpret_cast<uint2*>(&Bl[tid*BSTR + i*4]) = make_uint2(pk2(f.x,f.y), pk2(f.z,f.w));
      }
      __syncthreads();
#pragma unroll
      for (int ss = 0; ss < 2; ++ss){
        bf16x8 av = *reinterpret_cast<const bf16x8*>(&nei3[l31*NSTR + kb*32 + ss*16 + q*8]);
#pragma unroll
        for (int tj = 0; tj < 2; ++tj){
          bf16x8 bv = *reinterpret_cast<const bf16x8*>(&Bl[(w*64 + tj*32 + l31)*BSTR + ss*16 + q*8]);
          acc2[tj] = MFMA(av, bv, acc2[tj]);
        }
      }
    }
#pragma unroll
    for (int tj = 0; tj < 2; ++tj){
      int col = w*64 + tj*32 + l31;
      float b2v = b2[col];
#pragma unroll
      for (int r = 0; r < 16; ++r){
        int row = (r&3) + 8*(r>>2) + 4*q;
        out[((size_t)blockIdx.x*32 + row)*H + col] = acc2[tj][r] + b2v;
      }
    }
  }
}

extern "C" void kernel_launch(void* const* d_in, const int* in_sizes, int n_in,
                              void* d_out, int out_size, void* d_ws, size_t ws_size,
                              hipStream_t stream)
{
  (void)n_in; (void)out_size; (void)d_ws; (void)ws_size;
  const float* x   = (const float*)d_in[0];
  const float* Wb  = (const float*)d_in[1];
  const float* bb  = (const float*)d_in[2];
  const float* W1  = (const float*)d_in[3];
  const float* b1  = (const float*)d_in[4];
  const float* gam = (const float*)d_in[5];
  const float* bet = (const float*)d_in[6];
  const float* W2  = (const float*)d_in[7];
  const float* b2  = (const float*)d_in[8];
  // d_in[9] = perms: fixed A4 rotation table, baked into the kernel.
  float* out = (float*)d_out;

  const int N = in_sizes[0] / (4*256);   // 65536
  dim3 grid(N/32), block(256);
  tetra_fused<<<grid, block, 0, stream>>>(x, Wb, bb, W1, b1, gam, bet, W2, b2, out);
}

// Round 2
// 547.471 us; speedup vs baseline: 1.4162x; 1.4162x over previous
//
#include <hip/hip_runtime.h>
#include <cstdint>
#include <cstddef>

typedef __bf16 bf16x8 __attribute__((ext_vector_type(8)));
typedef float  f32x16 __attribute__((ext_vector_type(16)));

__device__ __forceinline__ unsigned f2bf_u(float f){
  unsigned u = __float_as_uint(f);
  return (u + 0x7FFFu + ((u >> 16) & 1u)) >> 16;   // RNE
}
__device__ __forceinline__ unsigned short f2bf(float f){ return (unsigned short)f2bf_u(f); }
__device__ __forceinline__ unsigned pk2(float a, float b){ return f2bf_u(a) | (f2bf_u(b) << 16); }

__device__ __forceinline__ float fast_tanh(float x){
  float xx = fminf(fmaxf(x, -8.0f), 8.0f);
  float e  = __builtin_amdgcn_exp2f(xx * 2.8853900817779268f);  // exp(2x)
  return 1.0f - 2.0f * __builtin_amdgcn_rcpf(e + 1.0f);
}

#define MFMA(a,b,c) __builtin_amdgcn_mfma_f32_32x32x16_bf16((a),(b),(c),0,0,0)

__device__ __forceinline__ void ld_lds16(const void* g, void* l){
  __builtin_amdgcn_global_load_lds(
      (const __attribute__((address_space(1))) unsigned int*)g,
      (__attribute__((address_space(3))) unsigned int*)l, 16, 0, 0);
}
__device__ __forceinline__ bf16x8 mk_frag(uint2 lo, uint2 hi){
  return __builtin_bit_cast(bf16x8, make_uint4(lo.x, lo.y, hi.x, hi.y));
}

// ---------- prep: Wb fp32 -> bf16, swizzled into stage-1 LDS chunk order ----------
// chunk t = gc*4+kq (16 KB): [ks(4)][tj(4)][c(4)][row(32)] x 8B slots.
// slot = Wb[k=tj][g=gc*32+row][K = kq*64 + ks*16 + c*4 .. +4]
__global__ void prep_wb(const float* __restrict__ Wb, unsigned short* __restrict__ dst){
  int s  = blockIdx.x*256 + threadIdx.x;     // 65536 slots of 8B
  int r  = s & 31;
  int c  = (s>>5) & 3;
  int tj = (s>>7) & 3;
  int ks = (s>>9) & 3;
  int kq = (s>>11) & 3;
  int gc = (s>>13) & 7;
  const float* src = Wb + ((size_t)tj*256 + gc*32 + r)*256 + kq*64 + ks*16 + c*4;
  float4 f = *reinterpret_cast<const float4*>(src);
  ushort4 o; o.x=f2bf(f.x); o.y=f2bf(f.y); o.z=f2bf(f.z); o.w=f2bf(f.w);
  *reinterpret_cast<ushort4*>(dst + (size_t)s*4) = o;
}

// ---------- prep: W1/W2 fp32 -> bf16, frag-major for direct global->reg B loads ----------
// per matrix: slot16 index = (ct*16+ks)*64 + lane; data = W[ct*32+(lane&31)][ks*16+(lane>>5)*8 ..+8]
__global__ void prep_w(const float* __restrict__ W1, const float* __restrict__ W2,
                       unsigned short* __restrict__ dst){
  int id = blockIdx.x*256 + threadIdx.x;     // 16384 slots of 16B (W1 then W2)
  const float* W = (id < 8192) ? W1 : W2;
  int s  = id & 8191;
  int l  = s & 63;
  int ks = (s>>6) & 15;
  int ct = (s>>10) & 7;
  const float* src = W + ((size_t)ct*32 + (l&31))*256 + ks*16 + (l>>5)*8;
  float4 f0 = *reinterpret_cast<const float4*>(src);
  float4 f1 = *reinterpret_cast<const float4*>(src + 4);
  ushort4 a, b;
  a.x=f2bf(f0.x); a.y=f2bf(f0.y); a.z=f2bf(f0.z); a.w=f2bf(f0.w);
  b.x=f2bf(f1.x); b.y=f2bf(f1.y); b.z=f2bf(f1.z); b.w=f2bf(f1.w);
  ushort4* d = reinterpret_cast<ushort4*>(dst + (size_t)id*8);
  d[0] = a; d[1] = b;
}

// ---------- main fused kernel ----------
// block = 256 thr (4 waves), 32 n (=128 x-rows). A in registers; Wb streamed
// via async global_load_lds double-buffer (1 barrier/chunk, 32 chunks);
// stages 2/3 read B frag-major straight from L2 (no barriers in k-loop).
__launch_bounds__(256, 3)
__global__ void tetra_main(const float* __restrict__ x,
                           const float* __restrict__ bb,
                           const float* __restrict__ b1,
                           const float* __restrict__ gam,
                           const float* __restrict__ bet,
                           const float* __restrict__ b2,
                           const unsigned short* __restrict__ wsWb,
                           const unsigned short* __restrict__ wsW1,
                           const unsigned short* __restrict__ wsW2,
                           float* __restrict__ out)
{
  __shared__ __align__(16) uint2 sbuf[2][2048];   // 2 x 16 KB Wb chunks
  __shared__ __align__(16) uint2 snei[2048];      // 16 KB: [c(64)][row(32)] 8B slots

  constexpr int PT[12][4] = {{0,1,2,3},{0,2,3,1},{0,3,1,2},{1,0,3,2},{1,2,0,3},{1,3,2,0},
                             {2,0,1,3},{2,1,3,0},{2,3,0,1},{3,0,2,1},{3,1,0,2},{3,2,1,0}};

  const int tid  = threadIdx.x;
  const int w    = tid >> 6;
  const int lane = tid & 63;
  const int l31  = lane & 31;
  const int q    = lane >> 5;

  // ---- A tile -> registers (bf16 packed). Lane: row l31 of wave slab, k-part q.
  uint4 fragA[16];
  {
    const float* arow = x + ((size_t)blockIdx.x*128 + (size_t)(w*32 + l31))*256 + q*8;
#pragma unroll
    for (int s = 0; s < 16; ++s){
      float4 f0 = *reinterpret_cast<const float4*>(arow + s*16);
      float4 f1 = *reinterpret_cast<const float4*>(arow + s*16 + 4);
      fragA[s] = make_uint4(pk2(f0.x,f0.y), pk2(f0.z,f0.w), pk2(f1.x,f1.y), pk2(f1.z,f1.w));
    }
  }

  // async stage of chunk t into sbuf[t&1]; wave w fills bytes [w*4096, w*4096+4096)
  auto stage = [&](int t){
    const char* g = (const char*)wsWb + (size_t)t*16384 + w*4096 + lane*16;
    char* lb = (char*)(&sbuf[t&1][0]) + w*4096;
#pragma unroll
    for (int i = 0; i < 4; ++i)
      ld_lds16(g + i*1024, lb + i*1024);
  };

  stage(0);

  // ================= stage 1 =================
  unsigned short* sn = (unsigned short*)snei;
  int t = 0;
  for (int gc = 0; gc < 8; ++gc){
    f32x16 acc[4];
#pragma unroll
    for (int k = 0; k < 4; ++k)
#pragma unroll
      for (int r = 0; r < 16; ++r) acc[k][r] = 0.0f;

#pragma unroll
    for (int kq = 0; kq < 4; ++kq, ++t){
      __syncthreads();                       // sbuf[t&1] ready; sbuf[(t+1)&1] free
      if (t < 31) stage(t+1);
      const uint2* B = sbuf[t&1];
      const int boff = q*64 + l31;           // (q*2)*32 + l31
#pragma unroll
      for (int ks = 0; ks < 4; ++ks){
        bf16x8 av = __builtin_bit_cast(bf16x8, fragA[kq*4 + ks]);
#pragma unroll
        for (int tj = 0; tj < 4; ++tj){
          int idx = (ks*16 + tj*4)*32 + boff;
          uint2 lo = B[idx], hi = B[idx + 32];
          acc[tj] = MFMA(av, mk_frag(lo, hi), acc[tj]);
        }
      }
    }

    // epilogue: bias + tanh, in-register 12-perm combine, nei/3 -> LDS bf16
    const int g0 = gc*32;
#pragma unroll
    for (int k = 0; k < 4; ++k){
      float bbv = bb[k*256 + g0 + l31];
#pragma unroll
      for (int r = 0; r < 16; ++r)
        acc[k][r] = fast_tanh(acc[k][r] + bbv);
    }
    const int col   = g0 + l31;
    const int sbase = (col>>2)*128 + (col&3);
#pragma unroll
    for (int nb = 0; nb < 4; ++nb){
      float s = 0.0f;
#pragma unroll
      for (int p = 0; p < 12; ++p){
        float v = acc[0][nb*4 + PT[p][0]] + acc[1][nb*4 + PT[p][1]]
                + acc[2][nb*4 + PT[p][2]] + acc[3][nb*4 + PT[p][3]];
        s += fmaxf(v, 0.0f);
      }
      sn[sbase + (w*8 + 2*nb + q)*4] = f2bf(s * (1.0f/3.0f));
    }
  }

  __syncthreads();   // nei3 complete

  // ================= stage 2: z = (nei/3)@W1^T ; h = relu(z*inv*gamma+beta) =================
  const int ct0 = w*2, ct1 = w*2 + 1;
  f32x16 a2[2];
#pragma unroll
  for (int j = 0; j < 2; ++j)
#pragma unroll
    for (int r = 0; r < 16; ++r) a2[j][r] = 0.0f;
  {
    const uint4* W1f = (const uint4*)wsW1;
    uint4 bp[8][2];
#pragma unroll
    for (int i = 0; i < 8; ++i){
      bp[i][0] = W1f[(ct0*16 + i)*64 + lane];
      bp[i][1] = W1f[(ct1*16 + i)*64 + lane];
    }
#pragma unroll
    for (int ks = 0; ks < 16; ++ks){
      int ai = (ks*4 + q*2)*32 + l31;
      uint2 lo = snei[ai], hi = snei[ai + 32];
      bf16x8 av = mk_frag(lo, hi);
      uint4 c0 = bp[ks&7][0], c1 = bp[ks&7][1];
      if (ks < 8){
        bp[ks][0] = W1f[(ct0*16 + ks + 8)*64 + lane];
        bp[ks][1] = W1f[(ct1*16 + ks + 8)*64 + lane];
      }
      a2[0] = MFMA(av, __builtin_bit_cast(bf16x8, c0), a2[0]);
      a2[1] = MFMA(av, __builtin_bit_cast(bf16x8, c1), a2[1]);
    }
  }
  __syncthreads();   // all snei reads done before overwrite
  {
    const float inv = 0.9999950000374998f;   // 1/sqrt(1+1e-5)
#pragma unroll
    for (int tj = 0; tj < 2; ++tj){
      int col = (w*2 + tj)*32 + l31;
      float b1v = b1[col], gv = gam[col], btv = bet[col];
#pragma unroll
      for (int r = 0; r < 16; ++r){
        int row = (r&3) + 8*(r>>2) + 4*q;
        float z  = a2[tj][r] + b1v;
        sn[(col>>2)*128 + row*4 + (col&3)] = f2bf(fmaxf(z*inv*gv + btv, 0.0f));
      }
    }
  }
  __syncthreads();   // h complete

  // ================= stage 3: out = h@W2^T + b2 =================
  f32x16 a3[2];
#pragma unroll
  for (int j = 0; j < 2; ++j)
#pragma unroll
    for (int r = 0; r < 16; ++r) a3[j][r] = 0.0f;
  {
    const uint4* W2f = (const uint4*)wsW2;
    uint4 bp[8][2];
#pragma unroll
    for (int i = 0; i < 8; ++i){
      bp[i][0] = W2f[(ct0*16 + i)*64 + lane];
      bp[i][1] = W2f[(ct1*16 + i)*64 + lane];
    }
#pragma unroll
    for (int ks = 0; ks < 16; ++ks){
      int ai = (ks*4 + q*2)*32 + l31;
      uint2 lo = snei[ai], hi = snei[ai + 32];
      bf16x8 av = mk_frag(lo, hi);
      uint4 c0 = bp[ks&7][0], c1 = bp[ks&7][1];
      if (ks < 8){
        bp[ks][0] = W2f[(ct0*16 + ks + 8)*64 + lane];
        bp[ks][1] = W2f[(ct1*16 + ks + 8)*64 + lane];
      }
      a3[0] = MFMA(av, __builtin_bit_cast(bf16x8, c0), a3[0]);
      a3[1] = MFMA(av, __builtin_bit_cast(bf16x8, c1), a3[1]);
    }
  }
#pragma unroll
  for (int tj = 0; tj < 2; ++tj){
    int col = (w*2 + tj)*32 + l31;
    float b2v = b2[col];
#pragma unroll
    for (int r = 0; r < 16; ++r){
      int row = (r&3) + 8*(r>>2) + 4*q;
      out[((size_t)blockIdx.x*32 + row)*256 + col] = a3[tj][r] + b2v;
    }
  }
}

extern "C" void kernel_launch(void* const* d_in, const int* in_sizes, int n_in,
                              void* d_out, int out_size, void* d_ws, size_t ws_size,
                              hipStream_t stream)
{
  (void)n_in; (void)out_size; (void)ws_size;
  const float* x   = (const float*)d_in[0];
  const float* Wb  = (const float*)d_in[1];
  const float* bb  = (const float*)d_in[2];
  const float* W1  = (const float*)d_in[3];
  const float* b1  = (const float*)d_in[4];
  const float* gam = (const float*)d_in[5];
  const float* bet = (const float*)d_in[6];
  const float* W2  = (const float*)d_in[7];
  const float* b2  = (const float*)d_in[8];
  // d_in[9] = perms: fixed A4 rotation table, baked into the kernel.
  float* out = (float*)d_out;

  unsigned short* wsWb = (unsigned short*)d_ws;        // 512 KB
  unsigned short* wsW1 = wsWb + 262144;                // 128 KB
  unsigned short* wsW2 = wsW1 + 65536;                 // 128 KB  (768 KB total)

  prep_wb<<<dim3(256), dim3(256), 0, stream>>>(Wb, wsWb);
  prep_w <<<dim3(64),  dim3(256), 0, stream>>>(W1, W2, wsW1);

  const int N = in_sizes[0] / (4*256);   // 65536
  tetra_main<<<dim3(N/32), dim3(256), 0, stream>>>(x, bb, b1, gam, bet, b2,
                                                   wsWb, wsW1, wsW2, out);
}